// Round 1
// baseline (298.532 us; speedup 1.0000x reference)
//
#include <hip/hip_runtime.h>
#include <hip/hip_bf16.h>
#include <cstdint>
#include <cstddef>

#define DEVFN __device__ __forceinline__

typedef __attribute__((ext_vector_type(8))) short short8;
typedef __attribute__((ext_vector_type(4))) float f32x4;
typedef __attribute__((ext_vector_type(4))) unsigned short us4;

static constexpr int S_LEN = 2048;
static constexpr int DM    = 1024;
static constexpr int H     = 16;
static constexpr int DK    = 64;
static constexpr int BATCH = 2;
static constexpr int MROWS = BATCH * S_LEN; // 4096

DEVFN unsigned short f2bf(float f) {
  union { float f; unsigned int u; } x; x.f = f;
  unsigned int r = x.u + 0x7fffu + ((x.u >> 16) & 1u);
  return (unsigned short)(r >> 16);
}

DEVFN f32x4 mfma16(short8 a, short8 b, f32x4 c) {
  return __builtin_amdgcn_mfma_f32_16x16x32_bf16(a, b, c, 0, 0, 0);
}

// ---------------------------------------------------------------------------
// Kernel 0: weight transpose + fp32->bf16.  W [K=1024][N=1024] -> Wt [N][K] bf16
// ---------------------------------------------------------------------------
__global__ __launch_bounds__(256) void wt_transpose(
    const float* __restrict__ Wq, const float* __restrict__ Wk,
    const float* __restrict__ Wv, const float* __restrict__ Wo,
    unsigned short* __restrict__ Tq, unsigned short* __restrict__ Tk,
    unsigned short* __restrict__ Tv, unsigned short* __restrict__ To)
{
  const float* W = blockIdx.z == 0 ? Wq : blockIdx.z == 1 ? Wk : blockIdx.z == 2 ? Wv : Wo;
  unsigned short* T = blockIdx.z == 0 ? Tq : blockIdx.z == 1 ? Tk : blockIdx.z == 2 ? Tv : To;
  __shared__ float tile[32][33];
  int n0 = blockIdx.x * 32, k0 = blockIdx.y * 32;
  int tx = threadIdx.x & 31, ty = threadIdx.x >> 5; // ty 0..7
#pragma unroll
  for (int i = 0; i < 4; ++i)
    tile[ty + 8 * i][tx] = W[(size_t)(k0 + ty + 8 * i) * DM + n0 + tx];
  __syncthreads();
#pragma unroll
  for (int i = 0; i < 4; ++i) {
    int n = ty + 8 * i;
    T[(size_t)(n0 + n) * DM + k0 + tx] = f2bf(tile[tx][n]);
  }
}

// ---------------------------------------------------------------------------
// Kernel 1: QKV projection GEMM. X fp32 [4096][1024] @ Wt^T -> bf16 outputs.
// z=0: Q [bh][s][d] (scaled 1/8), z=1: K [bh][s][d], z=2: V transposed [bh][d][s]
// ---------------------------------------------------------------------------
__global__ __launch_bounds__(256) void gemm_qkv(
    const float* __restrict__ Xq, const float* __restrict__ Xk, const float* __restrict__ Xv,
    const unsigned short* __restrict__ Tq, const unsigned short* __restrict__ Tk,
    const unsigned short* __restrict__ Tv,
    unsigned short* __restrict__ Qb, unsigned short* __restrict__ Kb,
    unsigned short* __restrict__ Vt)
{
  const int z = blockIdx.z;
  const float* X = z == 0 ? Xq : z == 1 ? Xk : Xv;
  const unsigned short* T = z == 0 ? Tq : z == 1 ? Tk : Tv;

  __shared__ __align__(16) unsigned short As[128][40];
  __shared__ __align__(16) unsigned short Bs[128][40];

  const int tid = threadIdx.x;
  const int lane = tid & 63, w = tid >> 6;
  const int wm = w >> 1, wn = w & 1;
  const int lr = lane & 15, lg = lane >> 4;
  const int m0 = blockIdx.x * 128, n0 = blockIdx.y * 128;

  f32x4 acc[4][4];
#pragma unroll
  for (int m = 0; m < 4; ++m)
#pragma unroll
    for (int n = 0; n < 4; ++n) acc[m][n] = (f32x4){0.f, 0.f, 0.f, 0.f};

  const int atk = tid & 7, atm = tid >> 3;  // A: 8 thr/row-chunk, col atk*4
  const int btk = tid & 3, btn = tid >> 2;  // B: 4 thr/row-chunk, col btk*8
  const int koff = lg * 8;

  for (int kt = 0; kt < DM / 32; ++kt) {
    const int k0 = kt * 32;
    // stage A (fp32 -> bf16): 128x32
#pragma unroll
    for (int i = 0; i < 4; ++i) {
      int r = atm + 32 * i;
      float4 v = *(const float4*)(X + (size_t)(m0 + r) * DM + k0 + atk * 4);
      us4 u; u.x = f2bf(v.x); u.y = f2bf(v.y); u.z = f2bf(v.z); u.w = f2bf(v.w);
      *(us4*)&As[r][atk * 4] = u;
    }
    // stage B (bf16): 128x32 from Wt [n][k]
#pragma unroll
    for (int i = 0; i < 2; ++i) {
      int r = btn + 64 * i;
      short8 v = *(const short8*)(T + (size_t)(n0 + r) * DM + k0 + btk * 8);
      *(short8*)&Bs[r][btk * 8] = v;
    }
    __syncthreads();
    short8 af[4], bfr[4];
#pragma unroll
    for (int m = 0; m < 4; ++m) af[m] = *(const short8*)&As[wm * 64 + m * 16 + lr][koff];
#pragma unroll
    for (int n = 0; n < 4; ++n) bfr[n] = *(const short8*)&Bs[wn * 64 + n * 16 + lr][koff];
#pragma unroll
    for (int m = 0; m < 4; ++m)
#pragma unroll
      for (int n = 0; n < 4; ++n) acc[m][n] = mfma16(af[m], bfr[n], acc[m][n]);
    __syncthreads();
  }

  const float scale = (z == 0) ? 0.125f : 1.0f;
  unsigned short* out = z == 0 ? Qb : z == 1 ? Kb : Vt;

  if (z < 2) {
#pragma unroll
    for (int m = 0; m < 4; ++m)
#pragma unroll
      for (int n = 0; n < 4; ++n) {
        int col = n0 + wn * 64 + n * 16 + lr;
        int h = col >> 6, d = col & 63;
#pragma unroll
        for (int r = 0; r < 4; ++r) {
          int row = m0 + wm * 64 + m * 16 + lg * 4 + r;
          int b = row >> 11, s = row & (S_LEN - 1);
          out[((size_t)(b * H + h) * S_LEN + s) * DK + d] = f2bf(acc[m][n][r] * scale);
        }
      }
  } else {
    // V transposed: [bh][d][s]; 4 regs = 4 consecutive s -> us4 store
#pragma unroll
    for (int m = 0; m < 4; ++m)
#pragma unroll
      for (int n = 0; n < 4; ++n) {
        int col = n0 + wn * 64 + n * 16 + lr;
        int h = col >> 6, d = col & 63;
        int row = m0 + wm * 64 + m * 16 + lg * 4;
        int b = row >> 11, s = row & (S_LEN - 1);
        us4 u;
#pragma unroll
        for (int r = 0; r < 4; ++r) u[r] = f2bf(acc[m][n][r]);
        *(us4*)(out + ((size_t)(b * H + h) * DK + d) * S_LEN + s) = u;
      }
  }
}

// ---------------------------------------------------------------------------
// Kernel 2: flash attention. Q,K [bh][s][64] bf16 (Q pre-scaled), V [bh][64][s].
// Output ctx bf16 [b*S + s][h*64 + d].
// Block: 4 waves, each wave owns 32 q-rows; KBLK=128 keys/iter.
// ---------------------------------------------------------------------------
__global__ __launch_bounds__(256) void attn(
    const unsigned short* __restrict__ Qg, const unsigned short* __restrict__ Kg,
    const unsigned short* __restrict__ Vg, unsigned short* __restrict__ ctx)
{
  __shared__ __align__(16) unsigned short Plds[4][32][136];
  const int tid = threadIdx.x, lane = tid & 63, w = tid >> 6;
  const int lr = lane & 15, lg = lane >> 4;
  const int bh = blockIdx.y, b = bh >> 4, h = bh & 15;
  const int q0 = blockIdx.x * 128 + w * 32;

  const unsigned short* Qbh = Qg + (size_t)bh * S_LEN * DK;
  const unsigned short* Kbh = Kg + (size_t)bh * S_LEN * DK;
  const unsigned short* Vbh = Vg + (size_t)bh * DK * S_LEN;

  short8 qa[2][2];
#pragma unroll
  for (int m = 0; m < 2; ++m)
#pragma unroll
    for (int kk = 0; kk < 2; ++kk)
      qa[m][kk] = *(const short8*)(Qbh + (size_t)(q0 + m * 16 + lr) * DK + kk * 32 + lg * 8);

  f32x4 o[2][4];
#pragma unroll
  for (int m = 0; m < 2; ++m)
#pragma unroll
    for (int n = 0; n < 4; ++n) o[m][n] = (f32x4){0.f, 0.f, 0.f, 0.f};
  float mrun[8], lrun[8];
#pragma unroll
  for (int i = 0; i < 8; ++i) { mrun[i] = -1e30f; lrun[i] = 0.f; }

  for (int kt = 0; kt < S_LEN / 128; ++kt) {
    const int kbase = kt * 128;
    f32x4 sc[2][8];
#pragma unroll
    for (int m = 0; m < 2; ++m)
#pragma unroll
      for (int n = 0; n < 8; ++n) sc[m][n] = (f32x4){0.f, 0.f, 0.f, 0.f};

    // QK^T: 32 MFMAs
#pragma unroll
    for (int kk = 0; kk < 2; ++kk) {
      const int dof = kk * 32 + lg * 8;
#pragma unroll
      for (int n = 0; n < 8; ++n) {
        short8 kb = *(const short8*)(Kbh + (size_t)(kbase + n * 16 + lr) * DK + dof);
        sc[0][n] = mfma16(qa[0][kk], kb, sc[0][n]);
        sc[1][n] = mfma16(qa[1][kk], kb, sc[1][n]);
      }
    }

    // online softmax (wave-parallel: 16-lane row groups reduce via shfl_xor)
#pragma unroll
    for (int m = 0; m < 2; ++m) {
#pragma unroll
      for (int r = 0; r < 4; ++r) {
        float mx = sc[m][0][r];
#pragma unroll
        for (int n = 1; n < 8; ++n) mx = fmaxf(mx, sc[m][n][r]);
        mx = fmaxf(mx, __shfl_xor(mx, 1, 64));
        mx = fmaxf(mx, __shfl_xor(mx, 2, 64));
        mx = fmaxf(mx, __shfl_xor(mx, 4, 64));
        mx = fmaxf(mx, __shfl_xor(mx, 8, 64));
        const int idx = m * 4 + r;
        float mnew = fmaxf(mrun[idx], mx);
        float alpha = __expf(mrun[idx] - mnew);
        float ps = 0.f;
#pragma unroll
        for (int n = 0; n < 8; ++n) {
          float p = __expf(sc[m][n][r] - mnew);
          sc[m][n][r] = p;
          ps += p;
        }
        ps += __shfl_xor(ps, 1, 64);
        ps += __shfl_xor(ps, 2, 64);
        ps += __shfl_xor(ps, 4, 64);
        ps += __shfl_xor(ps, 8, 64);
        lrun[idx] = lrun[idx] * alpha + ps;
        mrun[idx] = mnew;
#pragma unroll
        for (int n4 = 0; n4 < 4; ++n4) o[m][n4][r] *= alpha;
      }
    }

    // P (C-layout) -> LDS (A-layout source). Same-wave buffer: no barrier needed.
#pragma unroll
    for (int m = 0; m < 2; ++m)
#pragma unroll
      for (int n = 0; n < 8; ++n)
#pragma unroll
        for (int r = 0; r < 4; ++r)
          Plds[w][m * 16 + lg * 4 + r][n * 16 + lr] = f2bf(sc[m][n][r]);

    // PV: 32 MFMAs
#pragma unroll
    for (int kk = 0; kk < 4; ++kk) {
      short8 pa0 = *(const short8*)&Plds[w][lr][kk * 32 + lg * 8];
      short8 pa1 = *(const short8*)&Plds[w][16 + lr][kk * 32 + lg * 8];
#pragma unroll
      for (int n = 0; n < 4; ++n) {
        short8 vb = *(const short8*)(Vbh + (size_t)(n * 16 + lr) * S_LEN + kbase + kk * 32 + lg * 8);
        o[0][n] = mfma16(pa0, vb, o[0][n]);
        o[1][n] = mfma16(pa1, vb, o[1][n]);
      }
    }
  }

  // epilogue: normalize and store ctx [b*S+s][h*64+d]
#pragma unroll
  for (int m = 0; m < 2; ++m)
#pragma unroll
    for (int n = 0; n < 4; ++n) {
      int d = n * 16 + lr;
#pragma unroll
      for (int r = 0; r < 4; ++r) {
        int s = q0 + m * 16 + lg * 4 + r;
        float val = o[m][n][r] / lrun[m * 4 + r];
        ctx[((size_t)(b * S_LEN + s)) * DM + h * DK + d] = f2bf(val);
      }
    }
}

// ---------------------------------------------------------------------------
// Kernel 3: out projection + residual. ctx bf16 [4096][1024] @ Wo -> y fp32.
// ---------------------------------------------------------------------------
__global__ __launch_bounds__(256) void gemm_out(
    const unsigned short* __restrict__ C, const unsigned short* __restrict__ To,
    const float* __restrict__ resid, float* __restrict__ y)
{
  __shared__ __align__(16) unsigned short As[128][40];
  __shared__ __align__(16) unsigned short Bs[128][40];

  const int tid = threadIdx.x;
  const int lane = tid & 63, w = tid >> 6;
  const int wm = w >> 1, wn = w & 1;
  const int lr = lane & 15, lg = lane >> 4;
  const int m0 = blockIdx.x * 128, n0 = blockIdx.y * 128;

  f32x4 acc[4][4];
#pragma unroll
  for (int m = 0; m < 4; ++m)
#pragma unroll
    for (int n = 0; n < 4; ++n) acc[m][n] = (f32x4){0.f, 0.f, 0.f, 0.f};

  const int tk = tid & 3, tn = tid >> 2;
  const int koff = lg * 8;

  for (int kt = 0; kt < DM / 32; ++kt) {
    const int k0 = kt * 32;
#pragma unroll
    for (int i = 0; i < 2; ++i) {
      int r = tn + 64 * i;
      short8 v = *(const short8*)(C + (size_t)(m0 + r) * DM + k0 + tk * 8);
      *(short8*)&As[r][tk * 8] = v;
    }
#pragma unroll
    for (int i = 0; i < 2; ++i) {
      int r = tn + 64 * i;
      short8 v = *(const short8*)(To + (size_t)(n0 + r) * DM + k0 + tk * 8);
      *(short8*)&Bs[r][tk * 8] = v;
    }
    __syncthreads();
    short8 af[4], bfr[4];
#pragma unroll
    for (int m = 0; m < 4; ++m) af[m] = *(const short8*)&As[wm * 64 + m * 16 + lr][koff];
#pragma unroll
    for (int n = 0; n < 4; ++n) bfr[n] = *(const short8*)&Bs[wn * 64 + n * 16 + lr][koff];
#pragma unroll
    for (int m = 0; m < 4; ++m)
#pragma unroll
      for (int n = 0; n < 4; ++n) acc[m][n] = mfma16(af[m], bfr[n], acc[m][n]);
    __syncthreads();
  }

#pragma unroll
  for (int m = 0; m < 4; ++m)
#pragma unroll
    for (int n = 0; n < 4; ++n) {
      int col = n0 + wn * 64 + n * 16 + lr;
#pragma unroll
      for (int r = 0; r < 4; ++r) {
        int row = m0 + wm * 64 + m * 16 + lg * 4 + r;
        size_t idx = (size_t)row * DM + col;
        y[idx] = acc[m][n][r] + resid[idx];
      }
    }
}

// ---------------------------------------------------------------------------
// Kernel 4: LayerNorm over last dim (1024). gamma=1, beta=0, biased var.
// ---------------------------------------------------------------------------
__global__ __launch_bounds__(256) void lnorm(const float* __restrict__ y, float* __restrict__ out)
{
  const int row = blockIdx.x;
  const int tid = threadIdx.x;
  const float4 v = ((const float4*)(y + (size_t)row * DM))[tid];
  float s = v.x + v.y + v.z + v.w;
  float sq = v.x * v.x + v.y * v.y + v.z * v.z + v.w * v.w;
  s += __shfl_xor(s, 1, 64);  sq += __shfl_xor(sq, 1, 64);
  s += __shfl_xor(s, 2, 64);  sq += __shfl_xor(sq, 2, 64);
  s += __shfl_xor(s, 4, 64);  sq += __shfl_xor(sq, 4, 64);
  s += __shfl_xor(s, 8, 64);  sq += __shfl_xor(sq, 8, 64);
  s += __shfl_xor(s, 16, 64); sq += __shfl_xor(sq, 16, 64);
  s += __shfl_xor(s, 32, 64); sq += __shfl_xor(sq, 32, 64);
  __shared__ float ps[4], pq[4];
  int w = tid >> 6, lane = tid & 63;
  if (lane == 0) { ps[w] = s; pq[w] = sq; }
  __syncthreads();
  s = ps[0] + ps[1] + ps[2] + ps[3];
  sq = pq[0] + pq[1] + pq[2] + pq[3];
  float mean = s * (1.0f / DM);
  float var = sq * (1.0f / DM) - mean * mean;
  float rstd = rsqrtf(var + 1e-5f);
  float4 ov;
  ov.x = (v.x - mean) * rstd;
  ov.y = (v.y - mean) * rstd;
  ov.z = (v.z - mean) * rstd;
  ov.w = (v.w - mean) * rstd;
  ((float4*)(out + (size_t)row * DM))[tid] = ov;
}

// ---------------------------------------------------------------------------
extern "C" void kernel_launch(void* const* d_in, const int* in_sizes, int n_in,
                              void* d_out, int out_size, void* d_ws, size_t ws_size,
                              hipStream_t stream) {
  const float* Xq = (const float*)d_in[0];
  const float* Xk = (const float*)d_in[1];
  const float* Xv = (const float*)d_in[2];
  const float* Wq = (const float*)d_in[3];
  const float* Wk = (const float*)d_in[4];
  const float* Wv = (const float*)d_in[5];
  const float* Wo = (const float*)d_in[6];
  float* out = (float*)d_out;
  char* ws = (char*)d_ws;

  const size_t WT_BYTES  = (size_t)DM * DM * 2;            // 2 MB each
  const size_t QKV_BYTES = (size_t)BATCH * H * S_LEN * DK * 2; // 8 MB each
  const size_t CTX_BYTES = (size_t)MROWS * DM * 2;         // 8 MB

  size_t off = 0;
  auto take = [&](size_t bytes) { size_t o = off; off += (bytes + 255) & ~(size_t)255; return o; };
  unsigned short* Tq  = (unsigned short*)(ws + take(WT_BYTES));
  unsigned short* Tk  = (unsigned short*)(ws + take(WT_BYTES));
  unsigned short* Tv  = (unsigned short*)(ws + take(WT_BYTES));
  unsigned short* To  = (unsigned short*)(ws + take(WT_BYTES));
  size_t qb_off = take(QKV_BYTES);
  size_t kb_off = take(QKV_BYTES);
  unsigned short* Qb  = (unsigned short*)(ws + qb_off);
  unsigned short* Kb  = (unsigned short*)(ws + kb_off);
  unsigned short* Vt  = (unsigned short*)(ws + take(QKV_BYTES));
  unsigned short* Ctx = (unsigned short*)(ws + take(CTX_BYTES));
  float* y = (float*)(ws + qb_off); // alias Qb+Kb (dead after attention); 16 MB fits

  if (ws_size < off) return; // insufficient scratch -> fail validation loudly

  wt_transpose<<<dim3(32, 32, 4), 256, 0, stream>>>(Wq, Wk, Wv, Wo, Tq, Tk, Tv, To);
  gemm_qkv<<<dim3(32, 8, 3), 256, 0, stream>>>(Xq, Xk, Xv, Tq, Tk, Tv, Qb, Kb, Vt);
  attn<<<dim3(S_LEN / 128, BATCH * H), 256, 0, stream>>>(Qb, Kb, Vt, Ctx);
  gemm_out<<<dim3(MROWS / 128, DM / 128), 256, 0, stream>>>(Ctx, To, Xq, y);
  lnorm<<<MROWS, 256, 0, stream>>>(y, out);
}

// Round 2
// 214.789 us; speedup vs baseline: 1.3899x; 1.3899x over previous
//
#include <hip/hip_runtime.h>
#include <hip/hip_bf16.h>
#include <cstdint>
#include <cstddef>

#define DEVFN __device__ __forceinline__

typedef __attribute__((ext_vector_type(8))) short short8;
typedef __attribute__((ext_vector_type(4))) float f32x4;
typedef __attribute__((ext_vector_type(4))) unsigned short us4;

static constexpr int S_LEN = 2048;
static constexpr int DM    = 1024;
static constexpr int H     = 16;
static constexpr int DK    = 64;
static constexpr int BATCH = 2;
static constexpr int MROWS = BATCH * S_LEN; // 4096

DEVFN unsigned short f2bf(float f) {
  union { float f; unsigned int u; } x; x.f = f;
  unsigned int r = x.u + 0x7fffu + ((x.u >> 16) & 1u);
  return (unsigned short)(r >> 16);
}

DEVFN f32x4 mfma16(short8 a, short8 b, f32x4 c) {
  return __builtin_amdgcn_mfma_f32_16x16x32_bf16(a, b, c, 0, 0, 0);
}

DEVFN void gload_lds16(const void* g, void* l) {
  __builtin_amdgcn_global_load_lds(
      (const __attribute__((address_space(1))) void*)g,
      (__attribute__((address_space(3))) void*)l, 16, 0, 0);
}

// ---------------------------------------------------------------------------
// Kernel 0: weight transpose + fp32->bf16.  W [K=1024][N=1024] -> Wt [N][K] bf16
// ---------------------------------------------------------------------------
__global__ __launch_bounds__(256) void wt_transpose(
    const float* __restrict__ Wq, const float* __restrict__ Wk,
    const float* __restrict__ Wv, const float* __restrict__ Wo,
    unsigned short* __restrict__ Tq, unsigned short* __restrict__ Tk,
    unsigned short* __restrict__ Tv, unsigned short* __restrict__ To)
{
  const float* W = blockIdx.z == 0 ? Wq : blockIdx.z == 1 ? Wk : blockIdx.z == 2 ? Wv : Wo;
  unsigned short* T = blockIdx.z == 0 ? Tq : blockIdx.z == 1 ? Tk : blockIdx.z == 2 ? Tv : To;
  __shared__ float tile[32][33];
  int n0 = blockIdx.x * 32, k0 = blockIdx.y * 32;
  int tx = threadIdx.x & 31, ty = threadIdx.x >> 5; // ty 0..7
#pragma unroll
  for (int i = 0; i < 4; ++i)
    tile[ty + 8 * i][tx] = W[(size_t)(k0 + ty + 8 * i) * DM + n0 + tx];
  __syncthreads();
#pragma unroll
  for (int i = 0; i < 4; ++i) {
    int n = ty + 8 * i;
    T[(size_t)(n0 + n) * DM + k0 + tx] = f2bf(tile[tx][n]);
  }
}

// ---------------------------------------------------------------------------
// Kernel 1: QKV projection GEMM. X fp32 [4096][1024] @ Wt^T -> bf16 outputs.
// z=0: Q [bh][s][d] (scaled 1/8), z=1: K [bh][s][d], z=2: V transposed [bh][d][s]
// ---------------------------------------------------------------------------
__global__ __launch_bounds__(256) void gemm_qkv(
    const float* __restrict__ Xq, const float* __restrict__ Xk, const float* __restrict__ Xv,
    const unsigned short* __restrict__ Tq, const unsigned short* __restrict__ Tk,
    const unsigned short* __restrict__ Tv,
    unsigned short* __restrict__ Qb, unsigned short* __restrict__ Kb,
    unsigned short* __restrict__ Vt)
{
  const int z = blockIdx.z;
  const float* X = z == 0 ? Xq : z == 1 ? Xk : Xv;
  const unsigned short* T = z == 0 ? Tq : z == 1 ? Tk : Tv;

  __shared__ __align__(16) unsigned short As[128][40];
  __shared__ __align__(16) unsigned short Bs[128][40];

  const int tid = threadIdx.x;
  const int lane = tid & 63, w = tid >> 6;
  const int wm = w >> 1, wn = w & 1;
  const int lr = lane & 15, lg = lane >> 4;
  const int m0 = blockIdx.x * 128, n0 = blockIdx.y * 128;

  f32x4 acc[4][4];
#pragma unroll
  for (int m = 0; m < 4; ++m)
#pragma unroll
    for (int n = 0; n < 4; ++n) acc[m][n] = (f32x4){0.f, 0.f, 0.f, 0.f};

  const int atk = tid & 7, atm = tid >> 3;  // A: 8 thr/row-chunk, col atk*4
  const int btk = tid & 3, btn = tid >> 2;  // B: 4 thr/row-chunk, col btk*8
  const int koff = lg * 8;

  for (int kt = 0; kt < DM / 32; ++kt) {
    const int k0 = kt * 32;
    // stage A (fp32 -> bf16): 128x32
#pragma unroll
    for (int i = 0; i < 4; ++i) {
      int r = atm + 32 * i;
      float4 v = *(const float4*)(X + (size_t)(m0 + r) * DM + k0 + atk * 4);
      us4 u; u.x = f2bf(v.x); u.y = f2bf(v.y); u.z = f2bf(v.z); u.w = f2bf(v.w);
      *(us4*)&As[r][atk * 4] = u;
    }
    // stage B (bf16): 128x32 from Wt [n][k]
#pragma unroll
    for (int i = 0; i < 2; ++i) {
      int r = btn + 64 * i;
      short8 v = *(const short8*)(T + (size_t)(n0 + r) * DM + k0 + btk * 8);
      *(short8*)&Bs[r][btk * 8] = v;
    }
    __syncthreads();
    short8 af[4], bfr[4];
#pragma unroll
    for (int m = 0; m < 4; ++m) af[m] = *(const short8*)&As[wm * 64 + m * 16 + lr][koff];
#pragma unroll
    for (int n = 0; n < 4; ++n) bfr[n] = *(const short8*)&Bs[wn * 64 + n * 16 + lr][koff];
#pragma unroll
    for (int m = 0; m < 4; ++m)
#pragma unroll
      for (int n = 0; n < 4; ++n) acc[m][n] = mfma16(af[m], bfr[n], acc[m][n]);
    __syncthreads();
  }

  const float scale = (z == 0) ? 0.125f : 1.0f;
  unsigned short* out = z == 0 ? Qb : z == 1 ? Kb : Vt;

  if (z < 2) {
#pragma unroll
    for (int m = 0; m < 4; ++m)
#pragma unroll
      for (int n = 0; n < 4; ++n) {
        int col = n0 + wn * 64 + n * 16 + lr;
        int h = col >> 6, d = col & 63;
#pragma unroll
        for (int r = 0; r < 4; ++r) {
          int row = m0 + wm * 64 + m * 16 + lg * 4 + r;
          int b = row >> 11, s = row & (S_LEN - 1);
          out[((size_t)(b * H + h) * S_LEN + s) * DK + d] = f2bf(acc[m][n][r] * scale);
        }
      }
  } else {
    // V transposed: [bh][d][s]; 4 regs = 4 consecutive s -> us4 store
#pragma unroll
    for (int m = 0; m < 4; ++m)
#pragma unroll
      for (int n = 0; n < 4; ++n) {
        int col = n0 + wn * 64 + n * 16 + lr;
        int h = col >> 6, d = col & 63;
        int row = m0 + wm * 64 + m * 16 + lg * 4;
        int b = row >> 11, s = row & (S_LEN - 1);
        us4 u;
#pragma unroll
        for (int r = 0; r < 4; ++r) u[r] = f2bf(acc[m][n][r]);
        *(us4*)(out + ((size_t)(b * H + h) * DK + d) * S_LEN + s) = u;
      }
  }
}

// ---------------------------------------------------------------------------
// Kernel 2: flash attention, 2-phase pipelined.
// Q,K [bh][s][64] bf16 (Q pre-scaled), V [bh][64][s] bf16.
// Grid: 1024 blocks (32 qb x 32 bh), XCD-swizzled so each XCD owns 4 heads
// (K+V working set 2 MB -> L2-resident). Block: 4 waves, 16 q-rows/wave.
// KBLK=64 K/V tiles double-buffered in LDS via global_load_lds (width 16),
// staged with pre-swizzled global source (XOR (row&7)<<4) so LDS reads are
// bank-conflict-free. P round-trip swizzled the same way.
// LDS = 16K (K) + 16K (V) + 8K (P) = 40KB -> 4 blocks/CU.
// ---------------------------------------------------------------------------
__global__ __launch_bounds__(256, 4) void attn(
    const unsigned short* __restrict__ Qg, const unsigned short* __restrict__ Kg,
    const unsigned short* __restrict__ Vg, unsigned short* __restrict__ ctx)
{
  constexpr int KBLK = 64;
  constexpr int NT = S_LEN / KBLK; // 32
  __shared__ __align__(16) unsigned short Ks[2][KBLK][DK];
  __shared__ __align__(16) unsigned short Vs[2][DK][KBLK];
  __shared__ __align__(16) unsigned short Ps[4][16][KBLK];

  const int tid = threadIdx.x, lane = tid & 63, w = tid >> 6;
  const int lr = lane & 15, lg = lane >> 4;

  // bijective XCD swizzle: 1024 blocks = 8 XCDs x 128; XCD x owns bh [4x,4x+4)
  const int orig = blockIdx.x;
  const int id = (orig & 7) * 128 + (orig >> 3);
  const int bh = id >> 5, qb = id & 31;
  const int b = bh >> 4, h = bh & 15;
  const int q0 = qb * 64 + w * 16;

  const unsigned short* Qbh = Qg + (size_t)bh * S_LEN * DK;
  const unsigned short* Kbh = Kg + (size_t)bh * S_LEN * DK;
  const unsigned short* Vbh = Vg + (size_t)bh * DK * S_LEN;

  // staging lane constants: lane covers dest row (base + lane>>3), slot lane&7.
  // LDS slot s of row r holds logical 16B-chunk (s ^ (r&7)) -> fetch swizzled src.
  const int srow = lane >> 3;
  const int sslot = ((lane & 7) ^ srow) * 8; // in shorts

  auto stage = [&](int buf, int t) {
    const int kbase = t * KBLK;
#pragma unroll
    for (int c = 0; c < 2; ++c) {
      const int rbase = w * 8 + c * 32;
      gload_lds16(Kbh + (size_t)(kbase + rbase + srow) * DK + sslot, &Ks[buf][rbase][0]);
      gload_lds16(Vbh + (size_t)(rbase + srow) * S_LEN + kbase + sslot, &Vs[buf][rbase][0]);
    }
  };

  // Q fragments in registers (16 rows/wave)
  short8 qa[2];
#pragma unroll
  for (int kk = 0; kk < 2; ++kk)
    qa[kk] = *(const short8*)(Qbh + (size_t)(q0 + lr) * DK + kk * 32 + lg * 8);

  f32x4 o[4];
#pragma unroll
  for (int n = 0; n < 4; ++n) o[n] = (f32x4){0.f, 0.f, 0.f, 0.f};
  float mrun[4], lrun[4];
#pragma unroll
  for (int r = 0; r < 4; ++r) { mrun[r] = -1e30f; lrun[r] = 0.f; }

  const int kswz = (lr & 7) << 4; // read-side XOR swizzle (bytes)

  stage(0, 0);
  __syncthreads();

  int buf = 0;
  for (int t = 0; t < NT; ++t) {
    if (t + 1 < NT) stage(buf ^ 1, t + 1);

    // QK^T: 8 MFMAs
    f32x4 sc[4];
#pragma unroll
    for (int n = 0; n < 4; ++n) sc[n] = (f32x4){0.f, 0.f, 0.f, 0.f};
#pragma unroll
    for (int kk = 0; kk < 2; ++kk) {
      const int cb = (kk * 64 + lg * 16) ^ kswz;
#pragma unroll
      for (int n = 0; n < 4; ++n) {
        short8 kb = *(const short8*)((const char*)&Ks[buf][n * 16 + lr][0] + cb);
        sc[n] = mfma16(qa[kk], kb, sc[n]);
      }
    }

    // online softmax (rows lg*4+r, reduce over 16 lr lanes)
#pragma unroll
    for (int r = 0; r < 4; ++r) {
      float mx = fmaxf(fmaxf(sc[0][r], sc[1][r]), fmaxf(sc[2][r], sc[3][r]));
      mx = fmaxf(mx, __shfl_xor(mx, 1, 64));
      mx = fmaxf(mx, __shfl_xor(mx, 2, 64));
      mx = fmaxf(mx, __shfl_xor(mx, 4, 64));
      mx = fmaxf(mx, __shfl_xor(mx, 8, 64));
      float mnew = fmaxf(mrun[r], mx);
      float alpha = __expf(mrun[r] - mnew);
      mrun[r] = mnew;
      float ps = 0.f;
#pragma unroll
      for (int n = 0; n < 4; ++n) {
        float p = __expf(sc[n][r] - mnew);
        sc[n][r] = p;
        ps += p;
      }
      ps += __shfl_xor(ps, 1, 64);
      ps += __shfl_xor(ps, 2, 64);
      ps += __shfl_xor(ps, 4, 64);
      ps += __shfl_xor(ps, 8, 64);
      lrun[r] = lrun[r] * alpha + ps;
#pragma unroll
      for (int n = 0; n < 4; ++n) o[n][r] *= alpha;
    }

    // P (C-layout) -> LDS (swizzled); same-wave buffer, no barrier needed
#pragma unroll
    for (int r = 0; r < 4; ++r) {
      const int prow = lg * 4 + r;
      char* pb = (char*)&Ps[w][prow][0];
      const int pswz = (prow & 7) << 4;
#pragma unroll
      for (int n = 0; n < 4; ++n)
        *(unsigned short*)(pb + (((n * 16 + lr) * 2) ^ pswz)) = f2bf(sc[n][r]);
    }

    // PV: 8 MFMAs
#pragma unroll
    for (int kk = 0; kk < 2; ++kk) {
      const int cb = (kk * 64 + lg * 16) ^ kswz;
      short8 pa = *(const short8*)((const char*)&Ps[w][lr][0] + cb);
#pragma unroll
      for (int n = 0; n < 4; ++n) {
        short8 vb = *(const short8*)((const char*)&Vs[buf][n * 16 + lr][0] + cb);
        o[n] = mfma16(pa, vb, o[n]);
      }
    }

    __syncthreads(); // drains vmcnt(0): stage(t+1) landed; all waves done with buf
    buf ^= 1;
  }

  // epilogue: normalize, store ctx [b*S+s][h*64+d]
#pragma unroll
  for (int n = 0; n < 4; ++n) {
    int d = n * 16 + lr;
#pragma unroll
    for (int r = 0; r < 4; ++r) {
      int s = q0 + lg * 4 + r;
      float val = o[n][r] / lrun[r];
      ctx[((size_t)(b * S_LEN + s)) * DM + h * DK + d] = f2bf(val);
    }
  }
}

// ---------------------------------------------------------------------------
// Kernel 3: out projection + residual. ctx bf16 [4096][1024] @ Wo -> y fp32.
// ---------------------------------------------------------------------------
__global__ __launch_bounds__(256) void gemm_out(
    const unsigned short* __restrict__ C, const unsigned short* __restrict__ To,
    const float* __restrict__ resid, float* __restrict__ y)
{
  __shared__ __align__(16) unsigned short As[128][40];
  __shared__ __align__(16) unsigned short Bs[128][40];

  const int tid = threadIdx.x;
  const int lane = tid & 63, w = tid >> 6;
  const int wm = w >> 1, wn = w & 1;
  const int lr = lane & 15, lg = lane >> 4;
  const int m0 = blockIdx.x * 128, n0 = blockIdx.y * 128;

  f32x4 acc[4][4];
#pragma unroll
  for (int m = 0; m < 4; ++m)
#pragma unroll
    for (int n = 0; n < 4; ++n) acc[m][n] = (f32x4){0.f, 0.f, 0.f, 0.f};

  const int tk = tid & 3, tn = tid >> 2;
  const int koff = lg * 8;

  for (int kt = 0; kt < DM / 32; ++kt) {
    const int k0 = kt * 32;
#pragma unroll
    for (int i = 0; i < 2; ++i) {
      int r = tn + 64 * i;
      short8 v = *(const short8*)(C + (size_t)(m0 + r) * DM + k0 + tk * 8);
      *(short8*)&As[r][tk * 8] = v;
    }
#pragma unroll
    for (int i = 0; i < 2; ++i) {
      int r = tn + 64 * i;
      short8 v = *(const short8*)(To + (size_t)(n0 + r) * DM + k0 + tk * 8);
      *(short8*)&Bs[r][tk * 8] = v;
    }
    __syncthreads();
    short8 af[4], bfr[4];
#pragma unroll
    for (int m = 0; m < 4; ++m) af[m] = *(const short8*)&As[wm * 64 + m * 16 + lr][koff];
#pragma unroll
    for (int n = 0; n < 4; ++n) bfr[n] = *(const short8*)&Bs[wn * 64 + n * 16 + lr][koff];
#pragma unroll
    for (int m = 0; m < 4; ++m)
#pragma unroll
      for (int n = 0; n < 4; ++n) acc[m][n] = mfma16(af[m], bfr[n], acc[m][n]);
    __syncthreads();
  }

#pragma unroll
  for (int m = 0; m < 4; ++m)
#pragma unroll
    for (int n = 0; n < 4; ++n) {
      int col = n0 + wn * 64 + n * 16 + lr;
#pragma unroll
      for (int r = 0; r < 4; ++r) {
        int row = m0 + wm * 64 + m * 16 + lg * 4 + r;
        size_t idx = (size_t)row * DM + col;
        y[idx] = acc[m][n][r] + resid[idx];
      }
    }
}

// ---------------------------------------------------------------------------
// Kernel 4: LayerNorm over last dim (1024). gamma=1, beta=0, biased var.
// ---------------------------------------------------------------------------
__global__ __launch_bounds__(256) void lnorm(const float* __restrict__ y, float* __restrict__ out)
{
  const int row = blockIdx.x;
  const int tid = threadIdx.x;
  const float4 v = ((const float4*)(y + (size_t)row * DM))[tid];
  float s = v.x + v.y + v.z + v.w;
  float sq = v.x * v.x + v.y * v.y + v.z * v.z + v.w * v.w;
  s += __shfl_xor(s, 1, 64);  sq += __shfl_xor(sq, 1, 64);
  s += __shfl_xor(s, 2, 64);  sq += __shfl_xor(sq, 2, 64);
  s += __shfl_xor(s, 4, 64);  sq += __shfl_xor(sq, 4, 64);
  s += __shfl_xor(s, 8, 64);  sq += __shfl_xor(sq, 8, 64);
  s += __shfl_xor(s, 16, 64); sq += __shfl_xor(sq, 16, 64);
  s += __shfl_xor(s, 32, 64); sq += __shfl_xor(sq, 32, 64);
  __shared__ float ps[4], pq[4];
  int w = tid >> 6, lane = tid & 63;
  if (lane == 0) { ps[w] = s; pq[w] = sq; }
  __syncthreads();
  s = ps[0] + ps[1] + ps[2] + ps[3];
  sq = pq[0] + pq[1] + pq[2] + pq[3];
  float mean = s * (1.0f / DM);
  float var = sq * (1.0f / DM) - mean * mean;
  float rstd = rsqrtf(var + 1e-5f);
  float4 ov;
  ov.x = (v.x - mean) * rstd;
  ov.y = (v.y - mean) * rstd;
  ov.z = (v.z - mean) * rstd;
  ov.w = (v.w - mean) * rstd;
  ((float4*)(out + (size_t)row * DM))[tid] = ov;
}

// ---------------------------------------------------------------------------
extern "C" void kernel_launch(void* const* d_in, const int* in_sizes, int n_in,
                              void* d_out, int out_size, void* d_ws, size_t ws_size,
                              hipStream_t stream) {
  const float* Xq = (const float*)d_in[0];
  const float* Xk = (const float*)d_in[1];
  const float* Xv = (const float*)d_in[2];
  const float* Wq = (const float*)d_in[3];
  const float* Wk = (const float*)d_in[4];
  const float* Wv = (const float*)d_in[5];
  const float* Wo = (const float*)d_in[6];
  float* out = (float*)d_out;
  char* ws = (char*)d_ws;

  const size_t WT_BYTES  = (size_t)DM * DM * 2;            // 2 MB each
  const size_t QKV_BYTES = (size_t)BATCH * H * S_LEN * DK * 2; // 8 MB each
  const size_t CTX_BYTES = (size_t)MROWS * DM * 2;         // 8 MB

  size_t off = 0;
  auto take = [&](size_t bytes) { size_t o = off; off += (bytes + 255) & ~(size_t)255; return o; };
  unsigned short* Tq  = (unsigned short*)(ws + take(WT_BYTES));
  unsigned short* Tk  = (unsigned short*)(ws + take(WT_BYTES));
  unsigned short* Tv  = (unsigned short*)(ws + take(WT_BYTES));
  unsigned short* To  = (unsigned short*)(ws + take(WT_BYTES));
  size_t qb_off = take(QKV_BYTES);
  size_t kb_off = take(QKV_BYTES);
  unsigned short* Qb  = (unsigned short*)(ws + qb_off);
  unsigned short* Kb  = (unsigned short*)(ws + kb_off);
  unsigned short* Vt  = (unsigned short*)(ws + take(QKV_BYTES));
  unsigned short* Ctx = (unsigned short*)(ws + take(CTX_BYTES));
  float* y = (float*)(ws + qb_off); // alias Qb+Kb (dead after attention); 16 MB fits

  if (ws_size < off) return; // insufficient scratch -> fail validation loudly

  wt_transpose<<<dim3(32, 32, 4), 256, 0, stream>>>(Wq, Wk, Wv, Wo, Tq, Tk, Tv, To);
  gemm_qkv<<<dim3(32, 8, 3), 256, 0, stream>>>(Xq, Xk, Xv, Tq, Tk, Tv, Qb, Kb, Vt);
  attn<<<dim3(1024), 256, 0, stream>>>(Qb, Kb, Vt, Ctx);
  gemm_out<<<dim3(MROWS / 128, DM / 128), 256, 0, stream>>>(Ctx, To, Xq, y);
  lnorm<<<MROWS, 256, 0, stream>>>(y, out);
}

// Round 4
// 166.332 us; speedup vs baseline: 1.7948x; 1.2913x over previous
//
#include <hip/hip_runtime.h>
#include <hip/hip_bf16.h>
#include <cstdint>
#include <cstddef>

#define DEVFN __device__ __forceinline__

typedef __attribute__((ext_vector_type(8))) short short8;
typedef __attribute__((ext_vector_type(4))) float f32x4;
typedef __attribute__((ext_vector_type(16))) float f32x16;
typedef __attribute__((ext_vector_type(4))) unsigned short us4;

static constexpr int S_LEN = 2048;
static constexpr int DM    = 1024;
static constexpr int H     = 16;
static constexpr int DK    = 64;
static constexpr int BATCH = 2;
static constexpr int MROWS = BATCH * S_LEN; // 4096

DEVFN unsigned short f2bf(float f) {
  union { float f; unsigned int u; } x; x.f = f;
  unsigned int r = x.u + 0x7fffu + ((x.u >> 16) & 1u);
  return (unsigned short)(r >> 16);
}

DEVFN float fast_exp2(float x) { return __builtin_amdgcn_exp2f(x); }

DEVFN f32x4 mfma16(short8 a, short8 b, f32x4 c) {
  return __builtin_amdgcn_mfma_f32_16x16x32_bf16(a, b, c, 0, 0, 0);
}

DEVFN f32x16 mfma32(short8 a, short8 b, f32x16 c) {
  return __builtin_amdgcn_mfma_f32_32x32x16_bf16(a, b, c, 0, 0, 0);
}

DEVFN unsigned int cvtpk(float lo, float hi) {
  unsigned int r;
  asm("v_cvt_pk_bf16_f32 %0, %1, %2" : "=v"(r) : "v"(lo), "v"(hi));
  return r;
}

DEVFN void gload_lds16(const void* g, void* l) {
  __builtin_amdgcn_global_load_lds(
      (const __attribute__((address_space(1))) void*)g,
      (__attribute__((address_space(3))) void*)l, 16, 0, 0);
}

// ---------------------------------------------------------------------------
// Kernel 0: weight transpose + fp32->bf16.  W [K=1024][N=1024] -> Wt [N][K] bf16
// ---------------------------------------------------------------------------
__global__ __launch_bounds__(256) void wt_transpose(
    const float* __restrict__ Wq, const float* __restrict__ Wk,
    const float* __restrict__ Wv, const float* __restrict__ Wo,
    unsigned short* __restrict__ Tq, unsigned short* __restrict__ Tk,
    unsigned short* __restrict__ Tv, unsigned short* __restrict__ To)
{
  const float* W = blockIdx.z == 0 ? Wq : blockIdx.z == 1 ? Wk : blockIdx.z == 2 ? Wv : Wo;
  unsigned short* T = blockIdx.z == 0 ? Tq : blockIdx.z == 1 ? Tk : blockIdx.z == 2 ? Tv : To;
  __shared__ float tile[32][33];
  int n0 = blockIdx.x * 32, k0 = blockIdx.y * 32;
  int tx = threadIdx.x & 31, ty = threadIdx.x >> 5; // ty 0..7
#pragma unroll
  for (int i = 0; i < 4; ++i)
    tile[ty + 8 * i][tx] = W[(size_t)(k0 + ty + 8 * i) * DM + n0 + tx];
  __syncthreads();
#pragma unroll
  for (int i = 0; i < 4; ++i) {
    int n = ty + 8 * i;
    T[(size_t)(n0 + n) * DM + k0 + tx] = f2bf(tile[tx][n]);
  }
}

// ---------------------------------------------------------------------------
// Kernel 1: QKV projection GEMM. X fp32 [4096][1024] @ Wt^T -> bf16 outputs.
// z=0: Q [bh][s][d] (scaled by 0.125*log2e for exp2 softmax),
// z=1: K [bh][s][d], z=2: V transposed [bh][d][s]
// ---------------------------------------------------------------------------
__global__ __launch_bounds__(256) void gemm_qkv(
    const float* __restrict__ Xq, const float* __restrict__ Xk, const float* __restrict__ Xv,
    const unsigned short* __restrict__ Tq, const unsigned short* __restrict__ Tk,
    const unsigned short* __restrict__ Tv,
    unsigned short* __restrict__ Qb, unsigned short* __restrict__ Kb,
    unsigned short* __restrict__ Vt)
{
  const int z = blockIdx.z;
  const float* X = z == 0 ? Xq : z == 1 ? Xk : Xv;
  const unsigned short* T = z == 0 ? Tq : z == 1 ? Tk : Tv;

  __shared__ __align__(16) unsigned short As[128][40];
  __shared__ __align__(16) unsigned short Bs[128][40];

  const int tid = threadIdx.x;
  const int lane = tid & 63, w = tid >> 6;
  const int wm = w >> 1, wn = w & 1;
  const int lr = lane & 15, lg = lane >> 4;
  const int m0 = blockIdx.x * 128, n0 = blockIdx.y * 128;

  f32x4 acc[4][4];
#pragma unroll
  for (int m = 0; m < 4; ++m)
#pragma unroll
    for (int n = 0; n < 4; ++n) acc[m][n] = (f32x4){0.f, 0.f, 0.f, 0.f};

  const int atk = tid & 7, atm = tid >> 3;  // A: 8 thr/row-chunk, col atk*4
  const int btk = tid & 3, btn = tid >> 2;  // B: 4 thr/row-chunk, col btk*8
  const int koff = lg * 8;

  for (int kt = 0; kt < DM / 32; ++kt) {
    const int k0 = kt * 32;
    // stage A (fp32 -> bf16): 128x32
#pragma unroll
    for (int i = 0; i < 4; ++i) {
      int r = atm + 32 * i;
      float4 v = *(const float4*)(X + (size_t)(m0 + r) * DM + k0 + atk * 4);
      us4 u; u.x = f2bf(v.x); u.y = f2bf(v.y); u.z = f2bf(v.z); u.w = f2bf(v.w);
      *(us4*)&As[r][atk * 4] = u;
    }
    // stage B (bf16): 128x32 from Wt [n][k]
#pragma unroll
    for (int i = 0; i < 2; ++i) {
      int r = btn + 64 * i;
      short8 v = *(const short8*)(T + (size_t)(n0 + r) * DM + k0 + btk * 8);
      *(short8*)&Bs[r][btk * 8] = v;
    }
    __syncthreads();
    short8 af[4], bfr[4];
#pragma unroll
    for (int m = 0; m < 4; ++m) af[m] = *(const short8*)&As[wm * 64 + m * 16 + lr][koff];
#pragma unroll
    for (int n = 0; n < 4; ++n) bfr[n] = *(const short8*)&Bs[wn * 64 + n * 16 + lr][koff];
#pragma unroll
    for (int m = 0; m < 4; ++m)
#pragma unroll
      for (int n = 0; n < 4; ++n) acc[m][n] = mfma16(af[m], bfr[n], acc[m][n]);
    __syncthreads();
  }

  // Q pre-scale folds 1/sqrt(DK) and log2(e) so attention uses exp2 directly.
  const float scale = (z == 0) ? 0.125f * 1.44269504088896f : 1.0f;
  unsigned short* out = z == 0 ? Qb : z == 1 ? Kb : Vt;

  if (z < 2) {
#pragma unroll
    for (int m = 0; m < 4; ++m)
#pragma unroll
      for (int n = 0; n < 4; ++n) {
        int col = n0 + wn * 64 + n * 16 + lr;
        int h = col >> 6, d = col & 63;
#pragma unroll
        for (int r = 0; r < 4; ++r) {
          int row = m0 + wm * 64 + m * 16 + lg * 4 + r;
          int b = row >> 11, s = row & (S_LEN - 1);
          out[((size_t)(b * H + h) * S_LEN + s) * DK + d] = f2bf(acc[m][n][r] * scale);
        }
      }
  } else {
    // V transposed: [bh][d][s]; 4 regs = 4 consecutive s -> us4 store
#pragma unroll
    for (int m = 0; m < 4; ++m)
#pragma unroll
      for (int n = 0; n < 4; ++n) {
        int col = n0 + wn * 64 + n * 16 + lr;
        int h = col >> 6, d = col & 63;
        int row = m0 + wm * 64 + m * 16 + lg * 4;
        int b = row >> 11, s = row & (S_LEN - 1);
        us4 u;
#pragma unroll
        for (int r = 0; r < 4; ++r) u[r] = f2bf(acc[m][n][r]);
        *(us4*)(out + ((size_t)(b * H + h) * DK + d) * S_LEN + s) = u;
      }
  }
}

// ---------------------------------------------------------------------------
// Kernel 2: flash attention, swapped-QK^T 32x32 structure (guide §B / m214).
// Q,K [bh][s][64] bf16 (Q pre-scaled by 0.125*log2e), V [bh][64][s] bf16.
//
// Wave owns 32 q-rows; lane owns ONE q-row (q = lane&31; lanes l and l+32
// duplicate it). SC = mfma32(K, Q) gives C[k][q]: col=q lane-local -> row
// max/sum = 31 local ops + one shfl_xor(32). PV computed as O^T =
// mfma32(V^T, P): C[d][q] keeps q lane-local so m/l/rescale never cross
// lanes. P fragments built in-register: cvt_pk pairs + one shfl_xor(32)
// word exchange per 2 words.
// Grid: 512 blocks (16 qb x 32 bh), bijective XCD swizzle (4 heads/XCD ->
// K+V 2MB L2-resident). 2-phase global_load_lds double-buffer, XOR-swizzled
// via pre-swizzled global source. LDS 32KB.
// ---------------------------------------------------------------------------
__global__ __launch_bounds__(256, 2) void attn(
    const unsigned short* __restrict__ Qg, const unsigned short* __restrict__ Kg,
    const unsigned short* __restrict__ Vg, unsigned short* __restrict__ ctx)
{
  constexpr int KBLK = 64;
  constexpr int NT = S_LEN / KBLK; // 32
  __shared__ __align__(16) unsigned short Ks[2][KBLK][DK]; // [s][d]
  __shared__ __align__(16) unsigned short Vs[2][DK][KBLK]; // [d][s]

  const int tid = threadIdx.x, lane = tid & 63, w = tid >> 6;
  const int l31 = lane & 31, hi = lane >> 5;

  // bijective XCD swizzle: 512 blocks = 8 XCDs x 64; XCD x owns bh [4x,4x+4)
  const int orig = blockIdx.x;
  const int id = (orig & 7) * 64 + (orig >> 3);
  const int bh = id >> 4, qb = id & 15;
  const int b = bh >> 4, h = bh & 15;
  const int q = qb * 128 + w * 32 + l31; // this lane's q-row

  const unsigned short* Qbh = Qg + (size_t)bh * S_LEN * DK;
  const unsigned short* Kbh = Kg + (size_t)bh * S_LEN * DK;
  const unsigned short* Vbh = Vg + (size_t)bh * DK * S_LEN;

  // staging: dest row = rbase + lane/8 (linear), source chunk pre-swizzled
  const int srow = lane >> 3;
  const int sslot = ((lane & 7) ^ srow) * 8; // shorts

  auto stage = [&](int buf, int t) {
    const int kbase = t * KBLK;
#pragma unroll
    for (int c = 0; c < 2; ++c) {
      const int rbase = w * 8 + c * 32;
      gload_lds16(Kbh + (size_t)(kbase + rbase + srow) * DK + sslot, &Ks[buf][rbase][0]);
      gload_lds16(Vbh + (size_t)(rbase + srow) * S_LEN + kbase + sslot, &Vs[buf][rbase][0]);
    }
  };

  // Q fragments (B-operand): lane holds Q[q][kk*16 + hi*8 .. +8]
  short8 qf[4];
#pragma unroll
  for (int kk = 0; kk < 4; ++kk)
    qf[kk] = *(const short8*)(Qbh + (size_t)q * DK + kk * 16 + hi * 8);

  f32x16 o0, o1;
#pragma unroll
  for (int i = 0; i < 16; ++i) { o0[i] = 0.f; o1[i] = 0.f; }
  float mrun = -1e30f, lrun = 0.f;

  const int swz = (l31 & 7) << 4; // read-side XOR swizzle (bytes)

  stage(0, 0);
  __syncthreads();

  int buf = 0;
  for (int t = 0; t < NT; ++t) {
    if (t + 1 < NT) stage(buf ^ 1, t + 1);

    const char* Kb = (const char*)&Ks[buf][0][0];
    const char* Vb = (const char*)&Vs[buf][0][0];

    // QK^T swapped: SC[k][q] = sum_d K[k,d] Q[q,d]
    f32x16 s0, s1;
#pragma unroll
    for (int i = 0; i < 16; ++i) { s0[i] = 0.f; s1[i] = 0.f; }
#pragma unroll
    for (int kk = 0; kk < 4; ++kk) {
      const int cb = (kk * 32 + hi * 16) ^ swz;
      short8 ka0 = *(const short8*)(Kb + l31 * 128 + cb);
      short8 ka1 = *(const short8*)(Kb + (32 + l31) * 128 + cb);
      s0 = mfma32(ka0, qf[kk], s0);
      s1 = mfma32(ka1, qf[kk], s1);
    }

    // row max for this lane's q (local tree + one cross-half shuffle)
    float a[16];
#pragma unroll
    for (int i = 0; i < 16; ++i) a[i] = fmaxf(s0[i], s1[i]);
#pragma unroll
    for (int st = 8; st >= 1; st >>= 1)
#pragma unroll
      for (int i = 0; i < st; ++i) a[i] = fmaxf(a[i], a[i + st]);
    const float mx = fmaxf(a[0], __shfl_xor(a[0], 32, 64));

    const float mnew = fmaxf(mrun, mx);
    const float alpha = fast_exp2(mrun - mnew);
    mrun = mnew;

#pragma unroll
    for (int i = 0; i < 16; ++i) {
      s0[i] = fast_exp2(s0[i] - mnew);
      s1[i] = fast_exp2(s1[i] - mnew);
    }

    float d0[16];
#pragma unroll
    for (int i = 0; i < 16; ++i) d0[i] = s0[i] + s1[i];
#pragma unroll
    for (int st = 8; st >= 1; st >>= 1)
#pragma unroll
      for (int i = 0; i < st; ++i) d0[i] = d0[i] + d0[i + st];
    const float ps = d0[0] + __shfl_xor(d0[0], 32, 64);
    lrun = lrun * alpha + ps;

#pragma unroll
    for (int i = 0; i < 16; ++i) { o0[i] *= alpha; o1[i] *= alpha; }

    // Build P B-operand fragments per k-slice sl (k = sl*16 .. +15).
    short8 pf[4];
#pragma unroll
    for (int sl = 0; sl < 4; ++sl) {
      const f32x16& sv = (sl & 2) ? s1 : s0;
      const int base = (sl & 1) * 8;
      const unsigned int a01 = cvtpk(sv[base + 0], sv[base + 1]);
      const unsigned int a23 = cvtpk(sv[base + 2], sv[base + 3]);
      const unsigned int b01 = cvtpk(sv[base + 4], sv[base + 5]);
      const unsigned int b23 = cvtpk(sv[base + 6], sv[base + 7]);
      const unsigned int x0 = __shfl_xor(hi ? a01 : b01, 32, 64);
      const unsigned int x1 = __shfl_xor(hi ? a23 : b23, 32, 64);
      union { unsigned int u[4]; short8 v; } pu;
      pu.u[0] = hi ? x0 : a01;
      pu.u[1] = hi ? x1 : a23;
      pu.u[2] = hi ? b01 : x0;
      pu.u[3] = hi ? b23 : x1;
      pf[sl] = pu.v;
    }

    // PV as O^T: C[d][q] += sum_k V^T[d,k] P[k,q]
#pragma unroll
    for (int sl = 0; sl < 4; ++sl) {
      const int cb = (sl * 32 + hi * 16) ^ swz;
      short8 va0 = *(const short8*)(Vb + l31 * 128 + cb);
      short8 va1 = *(const short8*)(Vb + (32 + l31) * 128 + cb);
      o0 = mfma32(va0, pf[sl], o0);
      o1 = mfma32(va1, pf[sl], o1);
    }

    __syncthreads(); // barrier's vmcnt drain completes stage(t+1); buf safe to reuse
    buf ^= 1;
  }

  // epilogue: O^T C-layout: lane holds cols q (lane-local), rows d
  const float rinv = 1.0f / lrun;
  unsigned short* crow = ctx + ((size_t)(b * S_LEN + q)) * DM + h * DK;
#pragma unroll
  for (int n = 0; n < 2; ++n) {
#pragma unroll
    for (int r = 0; r < 16; r += 2) {
      const float v0 = (n ? o1[r] : o0[r]) * rinv;
      const float v1 = (n ? o1[r + 1] : o0[r + 1]) * rinv;
      const int d = (r & 3) + 8 * (r >> 2) + 4 * hi + 32 * n;
      *(unsigned int*)(crow + d) = cvtpk(v0, v1);
    }
  }
}

// ---------------------------------------------------------------------------
// Kernel 3: out projection + residual. ctx bf16 [4096][1024] @ Wo -> y fp32.
// ---------------------------------------------------------------------------
__global__ __launch_bounds__(256) void gemm_out(
    const unsigned short* __restrict__ C, const unsigned short* __restrict__ To,
    const float* __restrict__ resid, float* __restrict__ y)
{
  __shared__ __align__(16) unsigned short As[128][40];
  __shared__ __align__(16) unsigned short Bs[128][40];

  const int tid = threadIdx.x;
  const int lane = tid & 63, w = tid >> 6;
  const int wm = w >> 1, wn = w & 1;
  const int lr = lane & 15, lg = lane >> 4;
  const int m0 = blockIdx.x * 128, n0 = blockIdx.y * 128;

  f32x4 acc[4][4];
#pragma unroll
  for (int m = 0; m < 4; ++m)
#pragma unroll
    for (int n = 0; n < 4; ++n) acc[m][n] = (f32x4){0.f, 0.f, 0.f, 0.f};

  const int tk = tid & 3, tn = tid >> 2;
  const int koff = lg * 8;

  for (int kt = 0; kt < DM / 32; ++kt) {
    const int k0 = kt * 32;
#pragma unroll
    for (int i = 0; i < 2; ++i) {
      int r = tn + 64 * i;
      short8 v = *(const short8*)(C + (size_t)(m0 + r) * DM + k0 + tk * 8);
      *(short8*)&As[r][tk * 8] = v;
    }
#pragma unroll
    for (int i = 0; i < 2; ++i) {
      int r = tn + 64 * i;
      short8 v = *(const short8*)(To + (size_t)(n0 + r) * DM + k0 + tk * 8);
      *(short8*)&Bs[r][tk * 8] = v;
    }
    __syncthreads();
    short8 af[4], bfr[4];
#pragma unroll
    for (int m = 0; m < 4; ++m) af[m] = *(const short8*)&As[wm * 64 + m * 16 + lr][koff];
#pragma unroll
    for (int n = 0; n < 4; ++n) bfr[n] = *(const short8*)&Bs[wn * 64 + n * 16 + lr][koff];
#pragma unroll
    for (int m = 0; m < 4; ++m)
#pragma unroll
      for (int n = 0; n < 4; ++n) acc[m][n] = mfma16(af[m], bfr[n], acc[m][n]);
    __syncthreads();
  }

#pragma unroll
  for (int m = 0; m < 4; ++m)
#pragma unroll
    for (int n = 0; n < 4; ++n) {
      int col = n0 + wn * 64 + n * 16 + lr;
#pragma unroll
      for (int r = 0; r < 4; ++r) {
        int row = m0 + wm * 64 + m * 16 + lg * 4 + r;
        size_t idx = (size_t)row * DM + col;
        y[idx] = acc[m][n][r] + resid[idx];
      }
    }
}

// ---------------------------------------------------------------------------
// Kernel 4: LayerNorm over last dim (1024). gamma=1, beta=0, biased var.
// ---------------------------------------------------------------------------
__global__ __launch_bounds__(256) void lnorm(const float* __restrict__ y, float* __restrict__ out)
{
  const int row = blockIdx.x;
  const int tid = threadIdx.x;
  const float4 v = ((const float4*)(y + (size_t)row * DM))[tid];
  float s = v.x + v.y + v.z + v.w;
  float sq = v.x * v.x + v.y * v.y + v.z * v.z + v.w * v.w;
  s += __shfl_xor(s, 1, 64);  sq += __shfl_xor(sq, 1, 64);
  s += __shfl_xor(s, 2, 64);  sq += __shfl_xor(sq, 2, 64);
  s += __shfl_xor(s, 4, 64);  sq += __shfl_xor(sq, 4, 64);
  s += __shfl_xor(s, 8, 64);  sq += __shfl_xor(sq, 8, 64);
  s += __shfl_xor(s, 16, 64); sq += __shfl_xor(sq, 16, 64);
  s += __shfl_xor(s, 32, 64); sq += __shfl_xor(sq, 32, 64);
  __shared__ float ps[4], pq[4];
  int w = tid >> 6, lane = tid & 63;
  if (lane == 0) { ps[w] = s; pq[w] = sq; }
  __syncthreads();
  s = ps[0] + ps[1] + ps[2] + ps[3];
  sq = pq[0] + pq[1] + pq[2] + pq[3];
  float mean = s * (1.0f / DM);
  float var = sq * (1.0f / DM) - mean * mean;
  float rstd = rsqrtf(var + 1e-5f);
  float4 ov;
  ov.x = (v.x - mean) * rstd;
  ov.y = (v.y - mean) * rstd;
  ov.z = (v.z - mean) * rstd;
  ov.w = (v.w - mean) * rstd;
  ((float4*)(out + (size_t)row * DM))[tid] = ov;
}

// ---------------------------------------------------------------------------
extern "C" void kernel_launch(void* const* d_in, const int* in_sizes, int n_in,
                              void* d_out, int out_size, void* d_ws, size_t ws_size,
                              hipStream_t stream) {
  const float* Xq = (const float*)d_in[0];
  const float* Xk = (const float*)d_in[1];
  const float* Xv = (const float*)d_in[2];
  const float* Wq = (const float*)d_in[3];
  const float* Wk = (const float*)d_in[4];
  const float* Wv = (const float*)d_in[5];
  const float* Wo = (const float*)d_in[6];
  float* out = (float*)d_out;
  char* ws = (char*)d_ws;

  const size_t WT_BYTES  = (size_t)DM * DM * 2;            // 2 MB each
  const size_t QKV_BYTES = (size_t)BATCH * H * S_LEN * DK * 2; // 8 MB each
  const size_t CTX_BYTES = (size_t)MROWS * DM * 2;         // 8 MB

  size_t off = 0;
  auto take = [&](size_t bytes) { size_t o = off; off += (bytes + 255) & ~(size_t)255; return o; };
  unsigned short* Tq  = (unsigned short*)(ws + take(WT_BYTES));
  unsigned short* Tk  = (unsigned short*)(ws + take(WT_BYTES));
  unsigned short* Tv  = (unsigned short*)(ws + take(WT_BYTES));
  unsigned short* To  = (unsigned short*)(ws + take(WT_BYTES));
  size_t qb_off = take(QKV_BYTES);
  size_t kb_off = take(QKV_BYTES);
  unsigned short* Qb  = (unsigned short*)(ws + qb_off);
  unsigned short* Kb  = (unsigned short*)(ws + kb_off);
  unsigned short* Vt  = (unsigned short*)(ws + take(QKV_BYTES));
  unsigned short* Ctx = (unsigned short*)(ws + take(CTX_BYTES));
  float* y = (float*)(ws + qb_off); // alias Qb+Kb (dead after attention); 16 MB fits

  if (ws_size < off) return; // insufficient scratch -> fail validation loudly

  wt_transpose<<<dim3(32, 32, 4), 256, 0, stream>>>(Wq, Wk, Wv, Wo, Tq, Tk, Tv, To);
  gemm_qkv<<<dim3(32, 8, 3), 256, 0, stream>>>(Xq, Xk, Xv, Tq, Tk, Tv, Qb, Kb, Vt);
  attn<<<dim3(512), 256, 0, stream>>>(Qb, Kb, Vt, Ctx);
  gemm_out<<<dim3(MROWS / 128, DM / 128), 256, 0, stream>>>(Ctx, To, Xq, y);
  lnorm<<<MROWS, 256, 0, stream>>>(y, out);
}